// Round 1
// baseline (306.630 us; speedup 1.0000x reference)
//
#include <hip/hip_runtime.h>
#include <math.h>

#define NC 80
#define TOPKK 10
#define EPSF 1e-9f
#define IOU_EPSF 1e-7f
#define NA 8400
#define NGMAX 64

// IoU exactly as reference: inter/(a1+a2-inter+eps)
__device__ __forceinline__ float iou_xyxy(float px0, float py0, float px1, float py1,
                                          float parea,
                                          float gx0, float gy0, float gx1, float gy1,
                                          float garea) {
    float iw = fmaxf(fminf(px1, gx1) - fmaxf(px0, gx0), 0.0f);
    float ih = fmaxf(fminf(py1, gy1) - fmaxf(py0, gy0), 0.0f);
    float inter = iw * ih;
    return inter / (parea + garea - inter + IOU_EPSF);
}

// Kernel A: one block per (b,g). Compute masked align_metric column over all
// anchors into LDS, then 10 iterations of (value, lowest-index) argmax
// (matches jax.lax.top_k stable tie-breaking). Selected anchors get bit g set
// in the per-(b,a) uint64 bitmask (only for valid g => in_topk & valid folded).
__global__ __launch_bounds__(256) void topk_kernel(
    const float* __restrict__ pd_scores, const float* __restrict__ pd_bboxes,
    const float* __restrict__ anc, const int* __restrict__ gt_labels,
    const float* __restrict__ gt_bboxes, const int* __restrict__ mask_gt,
    unsigned long long* __restrict__ bits, int ng)
{
    __shared__ float vals[NA];
    __shared__ float redv[256];
    __shared__ int   redi[256];

    int bg = blockIdx.x;
    int b = bg / ng;
    int g = bg - b * ng;
    if (mask_gt[b * ng + g] == 0) return;  // invalid gt contributes nothing

    int lab = gt_labels[b * ng + g];
    const float4 gb = ((const float4*)gt_bboxes)[b * ng + g];
    float gx0 = gb.x, gy0 = gb.y, gx1 = gb.z, gy1 = gb.w;
    float garea = (gx1 - gx0) * (gy1 - gy0);

    const float* __restrict__ srow = pd_scores + ((long)b * NA) * NC + lab;
    const float4* __restrict__ pbb = (const float4*)(pd_bboxes + (long)b * NA * 4);

    for (int a = threadIdx.x; a < NA; a += 256) {
        float ax = anc[a * 2 + 0];
        float ay = anc[a * 2 + 1];
        float d0 = ax - gx0, d1 = ay - gy0, d2 = gx1 - ax, d3 = gy1 - ay;
        float dmin = fminf(fminf(d0, d1), fminf(d2, d3));
        float v = 0.0f;
        if (dmin > EPSF) {
            float4 pb = pbb[a];
            float parea = (pb.z - pb.x) * (pb.w - pb.y);
            float ov = iou_xyxy(pb.x, pb.y, pb.z, pb.w, parea, gx0, gy0, gx1, gy1, garea);
            float s = srow[(long)a * NC];
            v = sqrtf(s) * powf(ov, 6.0f);
        }
        vals[a] = v;
    }
    __syncthreads();

    for (int it = 0; it < TOPKK; ++it) {
        // per-thread scan, ascending index, strict > keeps lowest index on ties
        float bv = -1.0f; int bi = NA;
        for (int a = threadIdx.x; a < NA; a += 256) {
            float v = vals[a];
            if (v > bv) { bv = v; bi = a; }
        }
        redv[threadIdx.x] = bv;
        redi[threadIdx.x] = bi;
        __syncthreads();
        for (int s = 128; s > 0; s >>= 1) {
            if (threadIdx.x < s) {
                float vB = redv[threadIdx.x + s]; int iB = redi[threadIdx.x + s];
                float vA = redv[threadIdx.x];     int iA = redi[threadIdx.x];
                if (vB > vA || (vB == vA && iB < iA)) {
                    redv[threadIdx.x] = vB; redi[threadIdx.x] = iB;
                }
            }
            __syncthreads();
        }
        int sel = redi[0];
        if (threadIdx.x == 0) {
            atomicOr(&bits[(long)b * NA + sel], 1ull << g);
            vals[sel] = -2.0f;   // exclude from further iterations (all real vals >= 0)
        }
        __syncthreads();
    }
}

// Kernel B: one thread per (b, anchor). Recompute mask/iou/align (identical
// expression to kernel A), resolve positives, write labels/bboxes/fg/gt_idx
// and the per-anchor normalized t value.
__global__ __launch_bounds__(256) void assign_kernel(
    const float* __restrict__ pd_scores, const float* __restrict__ pd_bboxes,
    const float* __restrict__ anc, const int* __restrict__ gt_labels,
    const float* __restrict__ gt_bboxes, const int* __restrict__ mask_gt,
    const unsigned long long* __restrict__ bits,
    float* __restrict__ out_labels, float* __restrict__ out_bboxes,
    float* __restrict__ out_fg, float* __restrict__ out_tgt,
    float* __restrict__ t_ws, int ng, int blocksPerB)
{
    __shared__ float4 sgt[NGMAX];
    __shared__ float  sarea[NGMAX];
    __shared__ int    slab[NGMAX];
    __shared__ int    svalid[NGMAX];

    int b = blockIdx.x / blocksPerB;
    int a = (blockIdx.x - b * blocksPerB) * 256 + threadIdx.x;

    for (int g = threadIdx.x; g < ng; g += 256) {
        float4 gb = ((const float4*)gt_bboxes)[b * ng + g];
        sgt[g] = gb;
        sarea[g] = (gb.z - gb.x) * (gb.w - gb.y);
        slab[g] = gt_labels[b * ng + g];
        svalid[g] = mask_gt[b * ng + g];
    }
    __syncthreads();
    if (a >= NA) return;

    float ax = anc[a * 2 + 0];
    float ay = anc[a * 2 + 1];
    float4 pb = ((const float4*)pd_bboxes)[(long)b * NA + a];
    float parea = (pb.z - pb.x) * (pb.w - pb.y);
    unsigned long long w = bits[(long)b * NA + a];
    const float* __restrict__ srow = pd_scores + ((long)b * NA + a) * NC;

    int cnt = 0, pos_g = 0;
    float best_ov = -1.0f; int best_g = 0;
    float m_align = 0.0f, m_ov = 0.0f, t_raw = 0.0f;

    for (int g = 0; g < ng; ++g) {
        float4 gb = sgt[g];
        float d0 = ax - gb.x, d1 = ay - gb.y, d2 = gb.z - ax, d3 = gb.w - ay;
        float dmin = fminf(fminf(d0, d1), fminf(d2, d3));
        bool mask = (dmin > EPSF) && (svalid[g] != 0);
        float ov = 0.0f, al = 0.0f;
        if (mask) {
            ov = iou_xyxy(pb.x, pb.y, pb.z, pb.w, parea, gb.x, gb.y, gb.z, gb.w, sarea[g]);
            float s = srow[slab[g]];
            al = sqrtf(s) * powf(ov, 6.0f);
        }
        bool pos = mask && ((w >> g) & 1ull);
        if (pos) { if (cnt == 0) pos_g = g; cnt++; }
        if (ov > best_ov) { best_ov = ov; best_g = g; }  // first max wins (strict >)
        m_align = fmaxf(m_align, al);
        m_ov    = fmaxf(m_ov, ov);
        t_raw   = fmaxf(t_raw, al * ov);
    }

    int fg  = (cnt > 0) ? 1 : 0;
    int tgt = (cnt > 1) ? best_g : ((cnt == 1) ? pos_g : 0);

    int labi = slab[tgt]; if (labi < 0) labi = 0;
    long ba = (long)b * NA + a;
    out_labels[ba] = (float)labi;
    float4 tb = sgt[tgt];
    ((float4*)out_bboxes)[ba] = tb;
    out_fg[ba]  = (float)fg;
    out_tgt[ba] = (float)tgt;

    float t = 0.0f;
    if (fg) {
        float na_ = fmaxf(m_align, EPSF);
        float no_ = fmaxf(m_ov, EPSF);
        t = (t_raw / na_) / no_;
    }
    t_ws[ba] = t;
}

// Kernel C: streaming one-hot * t write for target_scores (86 MB, coalesced).
__global__ __launch_bounds__(256) void scores_kernel(
    const float* __restrict__ labels, const float* __restrict__ t_ws,
    float* __restrict__ out_scores, long total)
{
    long i = (long)blockIdx.x * 256 + threadIdx.x;
    if (i >= total) return;
    long ba = i / NC;
    int c = (int)(i - ba * NC);
    float lab = labels[ba];
    float t = t_ws[ba];
    out_scores[i] = ((float)c == lab) ? t : 0.0f;
}

extern "C" void kernel_launch(void* const* d_in, const int* in_sizes, int n_in,
                              void* d_out, int out_size, void* d_ws, size_t ws_size,
                              hipStream_t stream) {
    const float* pd_scores = (const float*)d_in[0];
    const float* pd_bboxes = (const float*)d_in[1];
    const float* anc       = (const float*)d_in[2];
    const int*   gt_labels = (const int*)d_in[3];
    const float* gt_bboxes = (const float*)d_in[4];
    const int*   mask_gt   = (const int*)d_in[5];

    int na = in_sizes[2] / 2;            // 8400
    int bs = in_sizes[0] / (na * NC);    // 32
    int ng = in_sizes[3] / bs;           // 64

    long nBA = (long)bs * na;
    float* out        = (float*)d_out;
    float* out_labels = out;                 // bs*na
    float* out_bboxes = out + nBA;           // bs*na*4
    float* out_scores = out + nBA * 5;       // bs*na*80
    float* out_fg     = out + nBA * 85;      // bs*na
    float* out_tgt    = out + nBA * 86;      // bs*na

    unsigned long long* bits = (unsigned long long*)d_ws;
    float* t_ws = (float*)((char*)d_ws + nBA * sizeof(unsigned long long));

    hipMemsetAsync(d_ws, 0, nBA * sizeof(unsigned long long), stream);

    topk_kernel<<<bs * ng, 256, 0, stream>>>(
        pd_scores, pd_bboxes, anc, gt_labels, gt_bboxes, mask_gt, bits, ng);

    int bpb = (na + 255) / 256;
    assign_kernel<<<bs * bpb, 256, 0, stream>>>(
        pd_scores, pd_bboxes, anc, gt_labels, gt_bboxes, mask_gt, bits,
        out_labels, out_bboxes, out_fg, out_tgt, t_ws, ng, bpb);

    long total = nBA * NC;
    scores_kernel<<<(int)((total + 255) / 256), 256, 0, stream>>>(
        out_labels, t_ws, out_scores, total);
}

// Round 2
// 221.980 us; speedup vs baseline: 1.3813x; 1.3813x over previous
//
#include <hip/hip_runtime.h>
#include <math.h>

#define NC 80
#define TOPKK 10
#define EPSF 1e-9f
#define IOU_EPSF 1e-7f
#define NA 8400
#define NGMAX 64

// IoU exactly as reference: inter/(a1+a2-inter+eps)
__device__ __forceinline__ float iou_xyxy(float px0, float py0, float px1, float py1,
                                          float parea,
                                          float gx0, float gy0, float gx1, float gy1,
                                          float garea) {
    float iw = fmaxf(fminf(px1, gx1) - fmaxf(px0, gx0), 0.0f);
    float ih = fmaxf(fminf(py1, gy1) - fmaxf(py0, gy0), 0.0f);
    float inter = iw * ih;
    return inter / (parea + garea - inter + IOU_EPSF);
}

// align metric (identical expression in both kernels): sqrt(s) * ov^6
__device__ __forceinline__ float align_metric(float s, float ov) {
    float ov2 = ov * ov;
    return sqrtf(s) * (ov2 * ov2 * ov2);
}

// Kernel A: one block per (b,g). Each thread keeps a register-resident sorted
// top-10 of its ~33 strided candidates, then 10 rounds of block argmax via
// 64-lane shuffle butterfly + 4-entry LDS hop (1 barrier/round).
// Key = (float_bits(v) << 32) | ~idx  — monotone for v>=0, lowest-idx tiebreak
// matching jax.lax.top_k.
__global__ __launch_bounds__(256) void topk_kernel(
    const float* __restrict__ pd_scores, const float* __restrict__ pd_bboxes,
    const float* __restrict__ anc, const int* __restrict__ gt_labels,
    const float* __restrict__ gt_bboxes, const int* __restrict__ mask_gt,
    unsigned long long* __restrict__ bits, int ng)
{
    __shared__ unsigned long long wkey[2][4];

    int bg = blockIdx.x;
    int b = bg / ng;
    int g = bg - b * ng;
    if (mask_gt[b * ng + g] == 0) return;  // invalid gt contributes nothing

    int lab = gt_labels[b * ng + g];
    const float4 gb = ((const float4*)gt_bboxes)[b * ng + g];
    float gx0 = gb.x, gy0 = gb.y, gx1 = gb.z, gy1 = gb.w;
    float garea = (gx1 - gx0) * (gy1 - gy0);

    const float* __restrict__ srow = pd_scores + ((long)b * NA) * NC + lab;
    const float4* __restrict__ pbb = (const float4*)(pd_bboxes + (long)b * NA * 4);

    // per-thread sorted (desc by value, ties keep earlier=lower index) top-10
    float lv[TOPKK];
    int   li[TOPKK];
#pragma unroll
    for (int j = 0; j < TOPKK; ++j) { lv[j] = -1.0f; li[j] = -1; }

    for (int a = threadIdx.x; a < NA; a += 256) {
        float ax = anc[a * 2 + 0];
        float ay = anc[a * 2 + 1];
        float d0 = ax - gx0, d1 = ay - gy0, d2 = gx1 - ax, d3 = gy1 - ay;
        float dmin = fminf(fminf(d0, d1), fminf(d2, d3));
        float v = 0.0f;
        if (dmin > EPSF) {
            float4 pb = pbb[a];
            float parea = (pb.z - pb.x) * (pb.w - pb.y);
            float ov = iou_xyxy(pb.x, pb.y, pb.z, pb.w, parea, gx0, gy0, gx1, gy1, garea);
            float s = srow[(long)a * NC];
            v = align_metric(s, ov);
        }
        // branchless sorted insert (only when it beats current 10th).
        // Indices scanned ascending, so on value ties the new element ranks
        // below existing ones: position p = #{j : lv[j] >= v}.
        if (v > lv[TOPKK - 1]) {
            float nv[TOPKK]; int ni[TOPKK];
#pragma unroll
            for (int j = 0; j < TOPKK; ++j) {
                bool keep = (lv[j] >= v);
                bool atp  = (j == 0) ? !keep : (!keep && (lv[j - 1] >= v));
                nv[j] = keep ? lv[j] : (atp ? v : lv[j - 1]);
                ni[j] = keep ? li[j] : (atp ? a : li[j - 1]);
            }
#pragma unroll
            for (int j = 0; j < TOPKK; ++j) { lv[j] = nv[j]; li[j] = ni[j]; }
        }
    }

    int lane = threadIdx.x & 63;
    int wid  = threadIdx.x >> 6;
    long bbase = (long)b * NA;

    for (int it = 0; it < TOPKK; ++it) {
        // propose head (sentinel lv<0 can never win; guard maps it to key 0)
        unsigned vb = __float_as_uint(lv[0]);
        unsigned long long myk = (lv[0] < 0.0f) ? 0ull
            : (((unsigned long long)vb << 32) | (unsigned)(~(unsigned)li[0]));

        unsigned long long k = myk;
#pragma unroll
        for (int off = 32; off > 0; off >>= 1) {
            unsigned long long o = __shfl_xor(k, off, 64);
            k = (o > k) ? o : k;
        }
        if (lane == 0) wkey[it & 1][wid] = k;
        __syncthreads();
        unsigned long long gk = wkey[it & 1][0];
        gk = (wkey[it & 1][1] > gk) ? wkey[it & 1][1] : gk;
        gk = (wkey[it & 1][2] > gk) ? wkey[it & 1][2] : gk;
        gk = (wkey[it & 1][3] > gk) ? wkey[it & 1][3] : gk;

        if (gk != 0ull && myk == gk) {
            // unique winner (idx unique across threads): record + pop head
            atomicOr(&bits[bbase + li[0]], 1ull << g);
#pragma unroll
            for (int j = 0; j < TOPKK - 1; ++j) { lv[j] = lv[j + 1]; li[j] = li[j + 1]; }
            lv[TOPKK - 1] = -1.0f; li[TOPKK - 1] = -1;
        }
        // no second barrier: wkey is double-buffered; the barrier of round
        // it+1 orders reads of buffer (it&1) before its reuse in round it+2.
    }
}

// Kernel B: one thread per (b, anchor). Recompute mask/iou/align (identical
// expression to kernel A), resolve positives, write labels/bboxes/fg/gt_idx
// and the per-anchor normalized t value.
__global__ __launch_bounds__(256) void assign_kernel(
    const float* __restrict__ pd_scores, const float* __restrict__ pd_bboxes,
    const float* __restrict__ anc, const int* __restrict__ gt_labels,
    const float* __restrict__ gt_bboxes, const int* __restrict__ mask_gt,
    const unsigned long long* __restrict__ bits,
    float* __restrict__ out_labels, float* __restrict__ out_bboxes,
    float* __restrict__ out_fg, float* __restrict__ out_tgt,
    float* __restrict__ t_ws, int ng, int blocksPerB)
{
    __shared__ float4 sgt[NGMAX];
    __shared__ float  sarea[NGMAX];
    __shared__ int    slab[NGMAX];
    __shared__ int    svalid[NGMAX];

    int b = blockIdx.x / blocksPerB;
    int a = (blockIdx.x - b * blocksPerB) * 256 + threadIdx.x;

    for (int g = threadIdx.x; g < ng; g += 256) {
        float4 gb = ((const float4*)gt_bboxes)[b * ng + g];
        sgt[g] = gb;
        sarea[g] = (gb.z - gb.x) * (gb.w - gb.y);
        slab[g] = gt_labels[b * ng + g];
        svalid[g] = mask_gt[b * ng + g];
    }
    __syncthreads();
    if (a >= NA) return;

    float ax = anc[a * 2 + 0];
    float ay = anc[a * 2 + 1];
    float4 pb = ((const float4*)pd_bboxes)[(long)b * NA + a];
    float parea = (pb.z - pb.x) * (pb.w - pb.y);
    unsigned long long w = bits[(long)b * NA + a];
    const float* __restrict__ srow = pd_scores + ((long)b * NA + a) * NC;

    int cnt = 0, pos_g = 0;
    float best_ov = -1.0f; int best_g = 0;
    float m_align = 0.0f, m_ov = 0.0f, t_raw = 0.0f;

    for (int g = 0; g < ng; ++g) {
        float4 gb = sgt[g];
        float d0 = ax - gb.x, d1 = ay - gb.y, d2 = gb.z - ax, d3 = gb.w - ay;
        float dmin = fminf(fminf(d0, d1), fminf(d2, d3));
        bool mask = (dmin > EPSF) && (svalid[g] != 0);
        float ov = 0.0f, al = 0.0f;
        if (mask) {
            ov = iou_xyxy(pb.x, pb.y, pb.z, pb.w, parea, gb.x, gb.y, gb.z, gb.w, sarea[g]);
            float s = srow[slab[g]];
            al = align_metric(s, ov);
        }
        bool pos = mask && ((w >> g) & 1ull);
        if (pos) { if (cnt == 0) pos_g = g; cnt++; }
        if (ov > best_ov) { best_ov = ov; best_g = g; }  // first max wins (strict >)
        m_align = fmaxf(m_align, al);
        m_ov    = fmaxf(m_ov, ov);
        t_raw   = fmaxf(t_raw, al * ov);
    }

    int fg  = (cnt > 0) ? 1 : 0;
    int tgt = (cnt > 1) ? best_g : ((cnt == 1) ? pos_g : 0);

    int labi = slab[tgt]; if (labi < 0) labi = 0;
    long ba = (long)b * NA + a;
    out_labels[ba] = (float)labi;
    float4 tb = sgt[tgt];
    ((float4*)out_bboxes)[ba] = tb;
    out_fg[ba]  = (float)fg;
    out_tgt[ba] = (float)tgt;

    float t = 0.0f;
    if (fg) {
        float na_ = fmaxf(m_align, EPSF);
        float no_ = fmaxf(m_ov, EPSF);
        t = (t_raw / na_) / no_;
    }
    t_ws[ba] = t;
}

// Kernel C: streaming one-hot * t write for target_scores (86 MB, float4).
// NC % 4 == 0 so each float4 group lies within exactly one anchor row.
__global__ __launch_bounds__(256) void scores_kernel(
    const float* __restrict__ labels, const float* __restrict__ t_ws,
    float4* __restrict__ out_scores, unsigned total4)
{
    unsigned i = blockIdx.x * 256u + threadIdx.x;
    if (i >= total4) return;
    unsigned ba = i / (NC / 4);              // magic-mul, constant divisor
    unsigned cg = (i - ba * (NC / 4)) * 4;   // class base of this group
    int lab = (int)labels[ba];
    float t = t_ws[ba];
    float4 o;
    o.x = ((int)cg     == lab) ? t : 0.0f;
    o.y = ((int)cg + 1 == lab) ? t : 0.0f;
    o.z = ((int)cg + 2 == lab) ? t : 0.0f;
    o.w = ((int)cg + 3 == lab) ? t : 0.0f;
    out_scores[i] = o;
}

extern "C" void kernel_launch(void* const* d_in, const int* in_sizes, int n_in,
                              void* d_out, int out_size, void* d_ws, size_t ws_size,
                              hipStream_t stream) {
    const float* pd_scores = (const float*)d_in[0];
    const float* pd_bboxes = (const float*)d_in[1];
    const float* anc       = (const float*)d_in[2];
    const int*   gt_labels = (const int*)d_in[3];
    const float* gt_bboxes = (const float*)d_in[4];
    const int*   mask_gt   = (const int*)d_in[5];

    int na = in_sizes[2] / 2;            // 8400
    int bs = in_sizes[0] / (na * NC);    // 32
    int ng = in_sizes[3] / bs;           // 64

    long nBA = (long)bs * na;
    float* out        = (float*)d_out;
    float* out_labels = out;                 // bs*na
    float* out_bboxes = out + nBA;           // bs*na*4
    float* out_scores = out + nBA * 5;       // bs*na*80
    float* out_fg     = out + nBA * 85;      // bs*na
    float* out_tgt    = out + nBA * 86;      // bs*na

    unsigned long long* bits = (unsigned long long*)d_ws;
    float* t_ws = (float*)((char*)d_ws + nBA * sizeof(unsigned long long));

    hipMemsetAsync(d_ws, 0, nBA * sizeof(unsigned long long), stream);

    topk_kernel<<<bs * ng, 256, 0, stream>>>(
        pd_scores, pd_bboxes, anc, gt_labels, gt_bboxes, mask_gt, bits, ng);

    int bpb = (na + 255) / 256;
    assign_kernel<<<bs * bpb, 256, 0, stream>>>(
        pd_scores, pd_bboxes, anc, gt_labels, gt_bboxes, mask_gt, bits,
        out_labels, out_bboxes, out_fg, out_tgt, t_ws, ng, bpb);

    unsigned total4 = (unsigned)(nBA * (NC / 4));
    scores_kernel<<<(int)((total4 + 255u) / 256u), 256, 0, stream>>>(
        out_labels, t_ws, (float4*)out_scores, total4);
}

// Round 3
// 217.818 us; speedup vs baseline: 1.4077x; 1.0191x over previous
//
#include <hip/hip_runtime.h>
#include <math.h>

#define NC 80
#define TOPKK 10
#define EPSF 1e-9f
#define IOU_EPSF 1e-7f
#define NA 8400
#define NGMAX 64

// IoU exactly as reference: inter/(a1+a2-inter+eps)
__device__ __forceinline__ float iou_xyxy(float px0, float py0, float px1, float py1,
                                          float parea,
                                          float gx0, float gy0, float gx1, float gy1,
                                          float garea) {
    float iw = fmaxf(fminf(px1, gx1) - fmaxf(px0, gx0), 0.0f);
    float ih = fmaxf(fminf(py1, gy1) - fmaxf(py0, gy0), 0.0f);
    float inter = iw * ih;
    return inter / (parea + garea - inter + IOU_EPSF);
}

// align metric (identical expression in both kernels): sqrt(s) * ov^6
__device__ __forceinline__ float align_metric(float s, float ov) {
    float ov2 = ov * ov;
    return sqrtf(s) * (ov2 * ov2 * ov2);
}

// Kernel A: one block per (b,g). Each thread keeps a register-resident sorted
// top-10 of its ~33 strided candidates, then 10 rounds of block argmax via
// 64-lane shuffle butterfly + 4-entry LDS hop (1 barrier/round).
// Key = (float_bits(v) << 32) | ~idx  — monotone for v>=0, lowest-idx tiebreak
// matching jax.lax.top_k.
__global__ __launch_bounds__(256) void topk_kernel(
    const float* __restrict__ pd_scores, const float* __restrict__ pd_bboxes,
    const float* __restrict__ anc, const int* __restrict__ gt_labels,
    const float* __restrict__ gt_bboxes, const int* __restrict__ mask_gt,
    unsigned long long* __restrict__ bits, int ng)
{
    __shared__ unsigned long long wkey[2][4];

    int bg = blockIdx.x;
    int b = bg / ng;
    int g = bg - b * ng;
    if (mask_gt[b * ng + g] == 0) return;  // invalid gt contributes nothing

    int lab = gt_labels[b * ng + g];
    const float4 gb = ((const float4*)gt_bboxes)[b * ng + g];
    float gx0 = gb.x, gy0 = gb.y, gx1 = gb.z, gy1 = gb.w;
    float garea = (gx1 - gx0) * (gy1 - gy0);

    const float* __restrict__ srow = pd_scores + ((long)b * NA) * NC + lab;
    const float4* __restrict__ pbb = (const float4*)(pd_bboxes + (long)b * NA * 4);

    // per-thread sorted (desc by value, ties keep earlier=lower index) top-10
    float lv[TOPKK];
    int   li[TOPKK];
#pragma unroll
    for (int j = 0; j < TOPKK; ++j) { lv[j] = -1.0f; li[j] = -1; }

    for (int a = threadIdx.x; a < NA; a += 256) {
        float ax = anc[a * 2 + 0];
        float ay = anc[a * 2 + 1];
        float d0 = ax - gx0, d1 = ay - gy0, d2 = gx1 - ax, d3 = gy1 - ay;
        float dmin = fminf(fminf(d0, d1), fminf(d2, d3));
        float v = 0.0f;
        if (dmin > EPSF) {
            float4 pb = pbb[a];
            float parea = (pb.z - pb.x) * (pb.w - pb.y);
            float ov = iou_xyxy(pb.x, pb.y, pb.z, pb.w, parea, gx0, gy0, gx1, gy1, garea);
            float s = srow[(long)a * NC];
            v = align_metric(s, ov);
        }
        // branchless sorted insert (only when it beats current 10th).
        if (v > lv[TOPKK - 1]) {
            float nv[TOPKK]; int ni[TOPKK];
#pragma unroll
            for (int j = 0; j < TOPKK; ++j) {
                bool keep = (lv[j] >= v);
                bool atp  = (j == 0) ? !keep : (!keep && (lv[j - 1] >= v));
                nv[j] = keep ? lv[j] : (atp ? v : lv[j - 1]);
                ni[j] = keep ? li[j] : (atp ? a : li[j - 1]);
            }
#pragma unroll
            for (int j = 0; j < TOPKK; ++j) { lv[j] = nv[j]; li[j] = ni[j]; }
        }
    }

    int lane = threadIdx.x & 63;
    int wid  = threadIdx.x >> 6;
    long bbase = (long)b * NA;

    for (int it = 0; it < TOPKK; ++it) {
        unsigned vb = __float_as_uint(lv[0]);
        unsigned long long myk = (lv[0] < 0.0f) ? 0ull
            : (((unsigned long long)vb << 32) | (unsigned)(~(unsigned)li[0]));

        unsigned long long k = myk;
#pragma unroll
        for (int off = 32; off > 0; off >>= 1) {
            unsigned long long o = __shfl_xor(k, off, 64);
            k = (o > k) ? o : k;
        }
        if (lane == 0) wkey[it & 1][wid] = k;
        __syncthreads();
        unsigned long long gk = wkey[it & 1][0];
        gk = (wkey[it & 1][1] > gk) ? wkey[it & 1][1] : gk;
        gk = (wkey[it & 1][2] > gk) ? wkey[it & 1][2] : gk;
        gk = (wkey[it & 1][3] > gk) ? wkey[it & 1][3] : gk;

        if (gk != 0ull && myk == gk) {
            atomicOr(&bits[bbase + li[0]], 1ull << g);
#pragma unroll
            for (int j = 0; j < TOPKK - 1; ++j) { lv[j] = lv[j + 1]; li[j] = li[j + 1]; }
            lv[TOPKK - 1] = -1.0f; li[TOPKK - 1] = -1;
        }
        // wkey double-buffered: next round's barrier orders reuse.
    }
}

// Kernel B (fused): one thread per (b, anchor) computes assignment + t, stages
// (label, t) in LDS, then the block writes its contiguous 256x80 score slab
// fully coalesced as float4. Also writes labels/bboxes/fg/gt_idx.
__global__ __launch_bounds__(256) void assign_scores_kernel(
    const float* __restrict__ pd_scores, const float* __restrict__ pd_bboxes,
    const float* __restrict__ anc, const int* __restrict__ gt_labels,
    const float* __restrict__ gt_bboxes, const int* __restrict__ mask_gt,
    const unsigned long long* __restrict__ bits,
    float* __restrict__ out_labels, float* __restrict__ out_bboxes,
    float* __restrict__ out_scores, float* __restrict__ out_fg,
    float* __restrict__ out_tgt, int ng, int blocksPerB)
{
    __shared__ float4 sgt[NGMAX];
    __shared__ float  sarea[NGMAX];
    __shared__ int    slab[NGMAX];
    __shared__ int    svalid[NGMAX];
    __shared__ int    plab[256];
    __shared__ float  pt[256];

    int b  = blockIdx.x / blocksPerB;
    int a0 = (blockIdx.x - b * blocksPerB) * 256;
    int a  = a0 + threadIdx.x;

    for (int g = threadIdx.x; g < ng; g += 256) {
        float4 gb = ((const float4*)gt_bboxes)[b * ng + g];
        sgt[g] = gb;
        sarea[g] = (gb.z - gb.x) * (gb.w - gb.y);
        slab[g] = gt_labels[b * ng + g];
        svalid[g] = mask_gt[b * ng + g];
    }
    __syncthreads();

    bool alive = (a < NA);
    int labi = 0; float t = 0.0f;

    if (alive) {
        float ax = anc[a * 2 + 0];
        float ay = anc[a * 2 + 1];
        float4 pb = ((const float4*)pd_bboxes)[(long)b * NA + a];
        float parea = (pb.z - pb.x) * (pb.w - pb.y);
        unsigned long long w = bits[(long)b * NA + a];
        const float* __restrict__ srow = pd_scores + ((long)b * NA + a) * NC;

        int cnt = 0, pos_g = 0;
        float best_ov = -1.0f; int best_g = 0;
        float m_align = 0.0f, m_ov = 0.0f, t_raw = 0.0f;

        for (int g = 0; g < ng; ++g) {
            float4 gb = sgt[g];
            float d0 = ax - gb.x, d1 = ay - gb.y, d2 = gb.z - ax, d3 = gb.w - ay;
            float dmin = fminf(fminf(d0, d1), fminf(d2, d3));
            bool mask = (dmin > EPSF) && (svalid[g] != 0);
            float ov = 0.0f, al = 0.0f;
            if (mask) {
                ov = iou_xyxy(pb.x, pb.y, pb.z, pb.w, parea, gb.x, gb.y, gb.z, gb.w, sarea[g]);
                float s = srow[slab[g]];
                al = align_metric(s, ov);
            }
            bool pos = mask && ((w >> g) & 1ull);
            if (pos) { if (cnt == 0) pos_g = g; cnt++; }
            if (ov > best_ov) { best_ov = ov; best_g = g; }  // first max wins
            m_align = fmaxf(m_align, al);
            m_ov    = fmaxf(m_ov, ov);
            t_raw   = fmaxf(t_raw, al * ov);
        }

        int fg  = (cnt > 0) ? 1 : 0;
        int tgt = (cnt > 1) ? best_g : ((cnt == 1) ? pos_g : 0);

        labi = slab[tgt]; if (labi < 0) labi = 0;
        long ba = (long)b * NA + a;
        out_labels[ba] = (float)labi;
        ((float4*)out_bboxes)[ba] = sgt[tgt];
        out_fg[ba]  = (float)fg;
        out_tgt[ba] = (float)tgt;

        if (fg) {
            float na_ = fmaxf(m_align, EPSF);
            float no_ = fmaxf(m_ov, EPSF);
            t = (t_raw / na_) / no_;
        }
    }

    plab[threadIdx.x] = labi;
    pt[threadIdx.x]   = t;
    __syncthreads();

    // coalesced score-slab write: rows [a0, a0+cnt) x 80 floats, contiguous
    int cnt_rows = NA - a0; if (cnt_rows > 256) cnt_rows = 256;
    int tot4 = cnt_rows * (NC / 4);
    float4* __restrict__ oslab = (float4*)(out_scores + ((long)b * NA + a0) * NC);
    for (int i = threadIdx.x; i < tot4; i += 256) {
        int al = i / (NC / 4);                 // const-div -> magic mul
        int cg = (i - al * (NC / 4)) * 4;
        int lab = plab[al];
        float tv = pt[al];
        float4 o;
        o.x = (cg     == lab) ? tv : 0.0f;
        o.y = (cg + 1 == lab) ? tv : 0.0f;
        o.z = (cg + 2 == lab) ? tv : 0.0f;
        o.w = (cg + 3 == lab) ? tv : 0.0f;
        oslab[i] = o;
    }
}

extern "C" void kernel_launch(void* const* d_in, const int* in_sizes, int n_in,
                              void* d_out, int out_size, void* d_ws, size_t ws_size,
                              hipStream_t stream) {
    const float* pd_scores = (const float*)d_in[0];
    const float* pd_bboxes = (const float*)d_in[1];
    const float* anc       = (const float*)d_in[2];
    const int*   gt_labels = (const int*)d_in[3];
    const float* gt_bboxes = (const float*)d_in[4];
    const int*   mask_gt   = (const int*)d_in[5];

    int na = in_sizes[2] / 2;            // 8400
    int bs = in_sizes[0] / (na * NC);    // 32
    int ng = in_sizes[3] / bs;           // 64

    long nBA = (long)bs * na;
    float* out        = (float*)d_out;
    float* out_labels = out;                 // bs*na
    float* out_bboxes = out + nBA;           // bs*na*4
    float* out_scores = out + nBA * 5;       // bs*na*80
    float* out_fg     = out + nBA * 85;      // bs*na
    float* out_tgt    = out + nBA * 86;      // bs*na

    unsigned long long* bits = (unsigned long long*)d_ws;

    hipMemsetAsync(d_ws, 0, nBA * sizeof(unsigned long long), stream);

    topk_kernel<<<bs * ng, 256, 0, stream>>>(
        pd_scores, pd_bboxes, anc, gt_labels, gt_bboxes, mask_gt, bits, ng);

    int bpb = (na + 255) / 256;
    assign_scores_kernel<<<bs * bpb, 256, 0, stream>>>(
        pd_scores, pd_bboxes, anc, gt_labels, gt_bboxes, mask_gt, bits,
        out_labels, out_bboxes, out_scores, out_fg, out_tgt, ng, bpb);
}

// Round 4
// 205.318 us; speedup vs baseline: 1.4934x; 1.0609x over previous
//
#include <hip/hip_runtime.h>
#include <math.h>

#define NC 80
#define TOPKK 10
#define EPSF 1e-9f
#define IOU_EPSF 1e-7f
#define NA 8400
#define NGMAX 64

// IoU exactly as reference: inter/(a1+a2-inter+eps)
__device__ __forceinline__ float iou_xyxy(float px0, float py0, float px1, float py1,
                                          float parea,
                                          float gx0, float gy0, float gx1, float gy1,
                                          float garea) {
    float iw = fmaxf(fminf(px1, gx1) - fmaxf(px0, gx0), 0.0f);
    float ih = fmaxf(fminf(py1, gy1) - fmaxf(py0, gy0), 0.0f);
    float inter = iw * ih;
    return inter / (parea + garea - inter + IOU_EPSF);
}

// align metric (identical expression in both kernels): sqrt(s) * ov^6
__device__ __forceinline__ float align_metric(float s, float ov) {
    float ov2 = ov * ov;
    return sqrtf(s) * (ov2 * ov2 * ov2);
}

// Kernel A: one block per (b,g). Register-resident per-thread sorted top-10,
// then 10 rounds of 64-lane shuffle-butterfly argmax + 4-entry LDS hop.
// Key = (float_bits(v) << 32) | ~idx  — lowest-idx tiebreak = jax.lax.top_k.
// XCD swizzle: all ng blocks of a batch land on one XCD (blockIdx%8) so the
// batch's score slab (~2.7 MB) is resident in that XCD's 4 MB L2 once.
__global__ __launch_bounds__(256) void topk_kernel(
    const float* __restrict__ pd_scores, const float* __restrict__ pd_bboxes,
    const float* __restrict__ anc, const int* __restrict__ gt_labels,
    const float* __restrict__ gt_bboxes, const int* __restrict__ mask_gt,
    unsigned long long* __restrict__ bits, int ng, int swz)
{
    __shared__ unsigned long long wkey[2][4];

    int b, g;
    if (swz) {
        int x = blockIdx.x & 7;          // XCD id heuristic
        int j = blockIdx.x >> 3;
        b = x * swz + j / ng;            // swz = bs/8
        g = j - (j / ng) * ng;
    } else {
        b = blockIdx.x / ng;
        g = blockIdx.x - b * ng;
    }
    if (mask_gt[b * ng + g] == 0) return;  // invalid gt contributes nothing

    int lab = gt_labels[b * ng + g];
    const float4 gb = ((const float4*)gt_bboxes)[b * ng + g];
    float gx0 = gb.x, gy0 = gb.y, gx1 = gb.z, gy1 = gb.w;
    float garea = (gx1 - gx0) * (gy1 - gy0);

    const float* __restrict__ srow = pd_scores + ((long)b * NA) * NC + lab;
    const float4* __restrict__ pbb = (const float4*)(pd_bboxes + (long)b * NA * 4);

    // per-thread sorted (desc, ties keep lower index) top-10
    float lv[TOPKK];
    int   li[TOPKK];
#pragma unroll
    for (int j = 0; j < TOPKK; ++j) { lv[j] = -1.0f; li[j] = -1; }

    for (int a = threadIdx.x; a < NA; a += 256) {
        float ax = anc[a * 2 + 0];
        float ay = anc[a * 2 + 1];
        float d0 = ax - gx0, d1 = ay - gy0, d2 = gx1 - ax, d3 = gy1 - ay;
        float dmin = fminf(fminf(d0, d1), fminf(d2, d3));
        float v = 0.0f;
        if (dmin > EPSF) {
            float4 pb = pbb[a];
            float parea = (pb.z - pb.x) * (pb.w - pb.y);
            float ov = iou_xyxy(pb.x, pb.y, pb.z, pb.w, parea, gx0, gy0, gx1, gy1, garea);
            float s = srow[(long)a * NC];
            v = align_metric(s, ov);
        }
        if (v > lv[TOPKK - 1]) {   // branchless sorted insert
            float nv[TOPKK]; int ni[TOPKK];
#pragma unroll
            for (int j = 0; j < TOPKK; ++j) {
                bool keep = (lv[j] >= v);
                bool atp  = (j == 0) ? !keep : (!keep && (lv[j - 1] >= v));
                nv[j] = keep ? lv[j] : (atp ? v : lv[j - 1]);
                ni[j] = keep ? li[j] : (atp ? a : li[j - 1]);
            }
#pragma unroll
            for (int j = 0; j < TOPKK; ++j) { lv[j] = nv[j]; li[j] = ni[j]; }
        }
    }

    int lane = threadIdx.x & 63;
    int wid  = threadIdx.x >> 6;
    long bbase = (long)b * NA;

    for (int it = 0; it < TOPKK; ++it) {
        unsigned vb = __float_as_uint(lv[0]);
        unsigned long long myk = (lv[0] < 0.0f) ? 0ull
            : (((unsigned long long)vb << 32) | (unsigned)(~(unsigned)li[0]));

        unsigned long long k = myk;
#pragma unroll
        for (int off = 32; off > 0; off >>= 1) {
            unsigned long long o = __shfl_xor(k, off, 64);
            k = (o > k) ? o : k;
        }
        if (lane == 0) wkey[it & 1][wid] = k;
        __syncthreads();
        unsigned long long gk = wkey[it & 1][0];
        gk = (wkey[it & 1][1] > gk) ? wkey[it & 1][1] : gk;
        gk = (wkey[it & 1][2] > gk) ? wkey[it & 1][2] : gk;
        gk = (wkey[it & 1][3] > gk) ? wkey[it & 1][3] : gk;

        if (gk != 0ull && myk == gk) {
            atomicOr(&bits[bbase + li[0]], 1ull << g);
#pragma unroll
            for (int j = 0; j < TOPKK - 1; ++j) { lv[j] = lv[j + 1]; li[j] = li[j + 1]; }
            lv[TOPKK - 1] = -1.0f; li[TOPKK - 1] = -1;
        }
        // wkey double-buffered: next round's barrier orders reuse.
    }
}

// Kernel B (fused): one thread per (b, anchor) computes assignment + t, stages
// (label, t) in LDS, then the block writes its contiguous 256x80 score slab
// fully coalesced as float4. mask_gt is a prefix (arange<num_gt), so the
// g-loop breaks at the first invalid g (block-uniform -> no divergence).
__global__ __launch_bounds__(256) void assign_scores_kernel(
    const float* __restrict__ pd_scores, const float* __restrict__ pd_bboxes,
    const float* __restrict__ anc, const int* __restrict__ gt_labels,
    const float* __restrict__ gt_bboxes, const int* __restrict__ mask_gt,
    const unsigned long long* __restrict__ bits,
    float* __restrict__ out_labels, float* __restrict__ out_bboxes,
    float* __restrict__ out_scores, float* __restrict__ out_fg,
    float* __restrict__ out_tgt, int ng, int blocksPerB)
{
    __shared__ float4 sgt[NGMAX];
    __shared__ float  sarea[NGMAX];
    __shared__ int    slab[NGMAX];
    __shared__ int    svalid[NGMAX];
    __shared__ int    plab[256];
    __shared__ float  pt[256];

    int b  = blockIdx.x / blocksPerB;
    int a0 = (blockIdx.x - b * blocksPerB) * 256;
    int a  = a0 + threadIdx.x;

    for (int g = threadIdx.x; g < ng; g += 256) {
        float4 gb = ((const float4*)gt_bboxes)[b * ng + g];
        sgt[g] = gb;
        sarea[g] = (gb.z - gb.x) * (gb.w - gb.y);
        slab[g] = gt_labels[b * ng + g];
        svalid[g] = mask_gt[b * ng + g];
    }
    __syncthreads();

    bool alive = (a < NA);
    int labi = 0; float t = 0.0f;

    if (alive) {
        float ax = anc[a * 2 + 0];
        float ay = anc[a * 2 + 1];
        float4 pb = ((const float4*)pd_bboxes)[(long)b * NA + a];
        float parea = (pb.z - pb.x) * (pb.w - pb.y);
        unsigned long long w = bits[(long)b * NA + a];
        const float* __restrict__ srow = pd_scores + ((long)b * NA + a) * NC;

        int cnt = 0, pos_g = 0;
        // init best at (ov=0, g=0): invalid/masked overlaps are exactly 0 in
        // the reference, and strict > with ascending g keeps the first max,
        // so skipping invalid g's preserves argmax semantics.
        float best_ov = 0.0f; int best_g = 0;
        float m_align = 0.0f, m_ov = 0.0f, t_raw = 0.0f;

        for (int g = 0; g < ng; ++g) {
            if (svalid[g] == 0) break;   // prefix property of mask_gt
            float4 gb = sgt[g];
            float d0 = ax - gb.x, d1 = ay - gb.y, d2 = gb.z - ax, d3 = gb.w - ay;
            float dmin = fminf(fminf(d0, d1), fminf(d2, d3));
            bool mask = (dmin > EPSF);
            float ov = 0.0f, al = 0.0f;
            if (mask) {
                ov = iou_xyxy(pb.x, pb.y, pb.z, pb.w, parea, gb.x, gb.y, gb.z, gb.w, sarea[g]);
                float s = srow[slab[g]];
                al = align_metric(s, ov);
            }
            bool pos = mask && ((w >> g) & 1ull);
            if (pos) { if (cnt == 0) pos_g = g; cnt++; }
            if (ov > best_ov) { best_ov = ov; best_g = g; }  // first max wins
            m_align = fmaxf(m_align, al);
            m_ov    = fmaxf(m_ov, ov);
            t_raw   = fmaxf(t_raw, al * ov);
        }

        int fg  = (cnt > 0) ? 1 : 0;
        int tgt = (cnt > 1) ? best_g : ((cnt == 1) ? pos_g : 0);

        labi = slab[tgt]; if (labi < 0) labi = 0;
        long ba = (long)b * NA + a;
        out_labels[ba] = (float)labi;
        ((float4*)out_bboxes)[ba] = sgt[tgt];
        out_fg[ba]  = (float)fg;
        out_tgt[ba] = (float)tgt;

        if (fg) {
            float na_ = fmaxf(m_align, EPSF);
            float no_ = fmaxf(m_ov, EPSF);
            t = (t_raw / na_) / no_;
        }
    }

    plab[threadIdx.x] = labi;
    pt[threadIdx.x]   = t;
    __syncthreads();

    // coalesced score-slab write: rows [a0, a0+cnt) x 80 floats, contiguous
    int cnt_rows = NA - a0; if (cnt_rows > 256) cnt_rows = 256;
    int tot4 = cnt_rows * (NC / 4);
    float4* __restrict__ oslab = (float4*)(out_scores + ((long)b * NA + a0) * NC);
    for (int i = threadIdx.x; i < tot4; i += 256) {
        int al = i / (NC / 4);                 // const-div -> magic mul
        int cg = (i - al * (NC / 4)) * 4;
        int lab = plab[al];
        float tv = pt[al];
        float4 o;
        o.x = (cg     == lab) ? tv : 0.0f;
        o.y = (cg + 1 == lab) ? tv : 0.0f;
        o.z = (cg + 2 == lab) ? tv : 0.0f;
        o.w = (cg + 3 == lab) ? tv : 0.0f;
        oslab[i] = o;
    }
}

extern "C" void kernel_launch(void* const* d_in, const int* in_sizes, int n_in,
                              void* d_out, int out_size, void* d_ws, size_t ws_size,
                              hipStream_t stream) {
    const float* pd_scores = (const float*)d_in[0];
    const float* pd_bboxes = (const float*)d_in[1];
    const float* anc       = (const float*)d_in[2];
    const int*   gt_labels = (const int*)d_in[3];
    const float* gt_bboxes = (const float*)d_in[4];
    const int*   mask_gt   = (const int*)d_in[5];

    int na = in_sizes[2] / 2;            // 8400
    int bs = in_sizes[0] / (na * NC);    // 32
    int ng = in_sizes[3] / bs;           // 64

    long nBA = (long)bs * na;
    float* out        = (float*)d_out;
    float* out_labels = out;                 // bs*na
    float* out_bboxes = out + nBA;           // bs*na*4
    float* out_scores = out + nBA * 5;       // bs*na*80
    float* out_fg     = out + nBA * 85;      // bs*na
    float* out_tgt    = out + nBA * 86;      // bs*na

    unsigned long long* bits = (unsigned long long*)d_ws;

    hipMemsetAsync(d_ws, 0, nBA * sizeof(unsigned long long), stream);

    int swz = (bs % 8 == 0) ? (bs / 8) : 0;  // batches per XCD; 0 disables
    topk_kernel<<<bs * ng, 256, 0, stream>>>(
        pd_scores, pd_bboxes, anc, gt_labels, gt_bboxes, mask_gt, bits, ng, swz);

    int bpb = (na + 255) / 256;
    assign_scores_kernel<<<bs * bpb, 256, 0, stream>>>(
        pd_scores, pd_bboxes, anc, gt_labels, gt_bboxes, mask_gt, bits,
        out_labels, out_bboxes, out_scores, out_fg, out_tgt, ng, bpb);
}